// Round 6
// baseline (396.670 us; speedup 1.0000x reference)
//
#include <hip/hip_runtime.h>
#include <math.h>

#define NSTATES 21
#define NPULSES 128
#define BATCH   8192
#define BPB     12   // batch elems per block: 4 waves x 3 per wave

typedef float v4f __attribute__((ext_vector_type(4)));

// R6 PROBE (on the fastest structure, R2): duplicate every output float4
// store into d_ws at the same offset -> exactly 2x global write volume,
// everything else identical. Distinguishes:
//   H1 write-bound (~4.2 TB/s effective): dur ~2x (390-440us)
//   H2 writes hidden under compute/DS:    dur ~1x (206-240us)
__global__ __launch_bounds__(256) void epg_mt_kernel(
    const float* __restrict__ fa_arr,
    const float* __restrict__ ph_arr,
    const float* __restrict__ T1f, const float* __restrict__ T2f,
    const float* __restrict__ T1b, const float* __restrict__ T2b,
    const float* __restrict__ kfp, const float* __restrict__ kbp,
    const float* __restrict__ B0p, const float* __restrict__ B1p,
    const float* __restrict__ wfp, const float* __restrict__ wbp,
    const int*   __restrict__ TRp,
    float* __restrict__ out,
    float* __restrict__ dup)     // nullptr if ws too small; else ws mirror
{
    __shared__ float lds[2][BPB * NSTATES * 10];   // 2 x 2520 floats = 20160 B

    const int tid  = threadIdx.x;
    const int lane = tid & 63;
    const int g    = lane / 21;               // 0..2 valid, 3 == idle lane 63
    const int s    = lane - g * 21;           // state 0..20
    const int lb   = (tid >> 6) * 3 + g;      // local batch index 0..11
    const int b0   = blockIdx.x * BPB;
    const int b    = b0 + lb;
    const bool valid = (g < 3) && (b < BATCH);
    const int bc   = valid ? b : 0;           // clamped for safe param loads

    for (int i = tid; i < 2 * BPB * NSTATES * 10; i += 256)
        ((float*)lds)[i] = 0.f;

    const float tr  = (float)TRp[0];
    const float dt  = tr * 0.001f;
    const float E1f = expf(-tr / T1f[bc]);
    const float E2f = expf(-tr / T2f[bc]);
    const float E1b = expf(-tr / T1b[bc]);
    const float kfdt = kfp[bc] * dt;
    const float kbdt = kbp[bc] * dt;
    const float phi  = 6.28318530717958647692f * B0p[bc] * dt;
    const float b0c  = cosf(phi), b0s = sinf(phi);
    const float wfv  = wfp[bc], wbv = wbp[bc];
    const float add0f = (s == 0) ? (1.0f - E1f) * wfv : 0.0f;
    const float add0b = (s == 0) ? (1.0f - E1b) * wbv : 0.0f;
    const float b1   = B1p[bc];

    float Fpr = 0.f, Fpi = 0.f, Fmr = 0.f, Fmi = 0.f;
    float Zf = (s == 0) ? wfv : 0.f;
    float Zb = (s == 0) ? wbv : 0.f;

    const int nb = (BATCH - b0 < BPB) ? (BATCH - b0) : BPB;
    const int n4 = (nb * NSTATES * 10) >> 2;             // float4s per pulse
    const size_t pstride = (size_t)BATCH * NSTATES * 10; // floats per pulse
    const size_t obase = (size_t)b0 * (NSTATES * 10);

    __syncthreads();   // LDS zero-init visible

    for (int p = 0; p < NPULSES; ++p) {
        const float fa = fa_arr[p];
        const float ph = ph_arr[p];

        // --- relax + exchange ---
        Fpr *= E2f; Fpi *= E2f; Fmr *= E2f; Fmi *= E2f;
        const float dZf = kbdt * Zb - kfdt * Zf;
        const float dZb = kfdt * Zf - kbdt * Zb;
        const float nZf1 = fmaf(Zf, E1f, add0f) + dZf;
        const float nZb1 = fmaf(Zb, E1b, add0b) + dZb;
        Zf = nZf1; Zb = nZb1;

        // --- B0 precession (free pool; bound F is zero) ---
        {
            const float r  = Fpr * b0c - Fpi * b0s;
            const float i_ = Fpr * b0s + Fpi * b0c;
            const float r2 = Fmr * b0c + Fmi * b0s;
            const float i2 = Fmi * b0c - Fmr * b0s;
            Fpr = r; Fpi = i_; Fmr = r2; Fmi = i2;
        }

        // --- RF pulse (free pool only) ---
        const float half = 0.5f * fa * b1;
        const float ca = __cosf(half), sa = __sinf(half);
        const float cph = __cosf(ph), sph = __sinf(ph);
        const float ca2 = ca * ca, sa2 = sa * sa, casa = ca * sa;
        const float cd  = ca2 - sa2;
        const float e2c = cph * cph - sph * sph;
        const float e2s = 2.f * cph * sph;
        const float t1r = Fmr * e2c + Fmi * e2s;     // conj(Fmf)*eib^2
        const float t1i = Fmr * e2s - Fmi * e2c;
        const float t2r = Fpr * e2c - Fpi * e2s;     // conj(Fpf)*conj(eib^2)
        const float t2i = -(Fpr * e2s) - Fpi * e2c;
        const float zc = Zf * cph, zs = Zf * sph;    // Zf * eib
        const float nFpr = ca2 * Fpr + sa2 * t1r - casa * zs;
        const float nFpi = ca2 * Fpi + sa2 * t1i + casa * zc;
        const float nFmr = sa2 * t2r + ca2 * Fmr - casa * zs;
        const float nFmi = sa2 * t2i + ca2 * Fmi - casa * zc;
        const float nZf = casa * ((Fpi * cph - Fpr * sph) - (Fmi * cph + Fmr * sph)) + cd * Zf;
        Fpr = nFpr; Fpi = nFpi; Fmr = nFmr; Fmi = nFmi; Zf = nZf;

        // --- EPG shift ---
        const float sFpr = __shfl_up(Fpr, 1);
        const float sFpi = __shfl_up(Fpi, 1);
        const float sZf  = __shfl_up(Zf, 1);
        const float sZb  = __shfl_up(Zb, 1);
        const float sFmr = __shfl_down(Fmr, 1);
        const float sFmi = __shfl_down(Fmi, 1);
        const bool s0 = (s == 0), sE = (s == NSTATES - 1);
        Fpr = s0 ? 0.f : sFpr;
        Fpi = s0 ? 0.f : sFpi;
        Zf  = s0 ? 0.f : sZf;
        Zb  = s0 ? 0.f : sZb;
        Fmr = sE ? 0.f : sFmr;
        Fmi = sE ? 0.f : sFmi;

        // --- stage nonzero fields into LDS (zero fields persist) ---
        if (valid) {
            float* dst = lds[p & 1] + lb * (NSTATES * 10) + s * 10;
            ((float2*)dst)[0] = make_float2(Fpr, Fpi);
            ((float2*)dst)[1] = make_float2(Fmr, Fmi);
            dst[4] = Zf;
            dst[9] = Zb;
        }
        __syncthreads();

        // --- block-cooperative coalesced dwordx4 store (+probe duplicate) ---
        const v4f* Ls = (const v4f*)(lds[p & 1]);
        const size_t off4 = (obase + (size_t)p * pstride) >> 2;
        v4f* og = ((v4f*)out) + off4;
        if (dup) {
            v4f* od = ((v4f*)dup) + off4;
            for (int i = tid; i < n4; i += 256) {
                v4f t = Ls[i];
                og[i] = t;
                od[i] = t;   // PROBE: identical write volume to scratch
            }
        } else {
            for (int i = tid; i < n4; i += 256)
                og[i] = Ls[i];
        }
    }
}

extern "C" void kernel_launch(void* const* d_in, const int* in_sizes, int n_in,
                              void* d_out, int out_size, void* d_ws, size_t ws_size,
                              hipStream_t stream) {
    const float* fa  = (const float*)d_in[0];
    const float* ph  = (const float*)d_in[1];
    const float* T1f = (const float*)d_in[2];
    const float* T2f = (const float*)d_in[3];
    const float* T1b = (const float*)d_in[4];
    const float* T2b = (const float*)d_in[5];
    const float* kf  = (const float*)d_in[6];
    const float* kb  = (const float*)d_in[7];
    const float* B0  = (const float*)d_in[8];
    const float* B1  = (const float*)d_in[9];
    const float* wf  = (const float*)d_in[10];
    const float* wb  = (const float*)d_in[11];
    const int*   TR  = (const int*)d_in[12];
    float* out = (float*)d_out;

    const size_t out_bytes = (size_t)NPULSES * BATCH * NSTATES * 10 * sizeof(float);
    float* dup = (ws_size >= out_bytes) ? (float*)d_ws : nullptr;

    const int blocks = (BATCH + BPB - 1) / BPB;   // 683
    epg_mt_kernel<<<blocks, 256, 0, stream>>>(fa, ph, T1f, T2f, T1b, T2b,
                                              kf, kb, B0, B1, wf, wb, TR, out, dup);
}

// Round 7
// 207.056 us; speedup vs baseline: 1.9158x; 1.9158x over previous
//
#include <hip/hip_runtime.h>
#include <math.h>

#define NSTATES 21
#define NPULSES 128
#define BATCH   8192
#define BPB     12                  // batch elems per block (3 per compute wave)
#define CHUNK   4                   // pulses per staged chunk
#define NCHUNK  (NPULSES / CHUNK)   // 32
#define RECF    (NSTATES * 10)      // 210 floats per (batch,pulse) record
#define PFLOATS (BPB * RECF)        // 2520 floats per pulse per block
#define N4FULL  (PFLOATS / 4)       // 630 float4 per pulse per block

typedef float v4f __attribute__((ext_vector_type(4)));

// R7: producer/consumer wave specialization.
//  - waves 0-3: compute EPG (3 batch elems each, lanes 0-20/21-41/42-62),
//    stage CHUNK pulses into double-buffered LDS. Never issue global stores.
//  - waves 4-7: pure writers. Per chunk: bulk ds_read_b128 then back-to-back
//    global_store_dwordx4 bursts (~10 per thread), mimicking the 6.8 TB/s
//    fill kernel's uninterrupted store stream. Never touch the EPG math.
//  - one lgkmcnt-only s_barrier per chunk; stores are never vmcnt-drained
//    inside the loop, so the write queue stays continuously fed.
__global__ __launch_bounds__(512) void epg_mt_kernel(
    const float* __restrict__ fa_arr,
    const float* __restrict__ ph_arr,
    const float* __restrict__ T1f, const float* __restrict__ T2f,
    const float* __restrict__ T1b, const float* __restrict__ T2b,
    const float* __restrict__ kfp, const float* __restrict__ kbp,
    const float* __restrict__ B0p, const float* __restrict__ B1p,
    const float* __restrict__ wfp, const float* __restrict__ wbp,
    const int*   __restrict__ TRp,
    float* __restrict__ out)
{
    // 2 x CHUNK x 2520 floats = 80,640 B
    __shared__ __attribute__((aligned(16))) float lds[2][CHUNK][PFLOATS];

    const int tid = threadIdx.x;
    const int wv  = tid >> 6;                  // 0..7

    // zero-init all LDS: always-zero record fields 5..8 are never rewritten,
    // so they persist as zero across all chunk reuses.
    for (int i = tid; i < 2 * CHUNK * PFLOATS; i += 512)
        ((float*)lds)[i] = 0.f;

    const int b0 = blockIdx.x * BPB;
    const int nb = (BATCH - b0 < BPB) ? (BATCH - b0) : BPB;   // 12 (8 for tail)
    const int n4 = (nb * RECF) >> 2;                          // 630 (420 tail)
    const size_t pstride4 = ((size_t)BATCH * RECF) >> 2;      // float4 per slab
    v4f* outb4 = ((v4f*)out) + (size_t)blockIdx.x * N4FULL;   // 16B-aligned

    if (wv < 4) {
        // ---------------- compute role ----------------
        const int lane = tid & 63;
        const int g    = lane / 21;            // 0..2 valid, 3 == lane 63 idle
        const int s    = lane - g * 21;        // state 0..20
        const int lb   = wv * 3 + g;           // local batch 0..11
        const bool valid = (g < 3) && (lb < nb);
        const int bc   = valid ? (b0 + lb) : 0;

        const float tr  = (float)TRp[0];
        const float dt  = tr * 0.001f;
        const float E1f = expf(-tr / T1f[bc]);
        const float E2f = expf(-tr / T2f[bc]);
        const float E1b = expf(-tr / T1b[bc]);
        const float kfdt = kfp[bc] * dt;
        const float kbdt = kbp[bc] * dt;
        const float phi  = 6.28318530717958647692f * B0p[bc] * dt;
        const float b0c  = cosf(phi), b0s = sinf(phi);
        const float wfv  = wfp[bc], wbv = wbp[bc];
        const float add0f = (s == 0) ? (1.0f - E1f) * wfv : 0.0f;
        const float add0b = (s == 0) ? (1.0f - E1b) * wbv : 0.0f;
        const float b1   = B1p[bc];

        float Fpr = 0.f, Fpi = 0.f, Fmr = 0.f, Fmi = 0.f;
        float Zf = (s == 0) ? wfv : 0.f;
        float Zb = (s == 0) ? wbv : 0.f;

        auto step = [&](float fa, float ph) {
            Fpr *= E2f; Fpi *= E2f; Fmr *= E2f; Fmi *= E2f;
            const float dZf = kbdt * Zb - kfdt * Zf;
            const float dZb = kfdt * Zf - kbdt * Zb;
            const float nZf1 = fmaf(Zf, E1f, add0f) + dZf;
            const float nZb1 = fmaf(Zb, E1b, add0b) + dZb;
            Zf = nZf1; Zb = nZb1;
            {   // B0 precession (free pool; bound-pool F identically zero)
                const float r  = Fpr * b0c - Fpi * b0s;
                const float i_ = Fpr * b0s + Fpi * b0c;
                const float r2 = Fmr * b0c + Fmi * b0s;
                const float i2 = Fmi * b0c - Fmr * b0s;
                Fpr = r; Fpi = i_; Fmr = r2; Fmi = i2;
            }
            const float half = 0.5f * fa * b1;
            const float ca = __cosf(half), sa = __sinf(half);
            const float cph = __cosf(ph), sph = __sinf(ph);
            const float ca2 = ca * ca, sa2 = sa * sa, casa = ca * sa;
            const float cd  = ca2 - sa2;
            const float e2c = cph * cph - sph * sph;
            const float e2s = 2.f * cph * sph;
            const float t1r = Fmr * e2c + Fmi * e2s;     // conj(Fmf)*eib^2
            const float t1i = Fmr * e2s - Fmi * e2c;
            const float t2r = Fpr * e2c - Fpi * e2s;     // conj(Fpf)*conj(eib^2)
            const float t2i = -(Fpr * e2s) - Fpi * e2c;
            const float zc = Zf * cph, zs = Zf * sph;    // Zf * eib
            const float nFpr = ca2 * Fpr + sa2 * t1r - casa * zs;
            const float nFpi = ca2 * Fpi + sa2 * t1i + casa * zc;
            const float nFmr = sa2 * t2r + ca2 * Fmr - casa * zs;
            const float nFmi = sa2 * t2i + ca2 * Fmi - casa * zc;
            const float nZf = casa * ((Fpi * cph - Fpr * sph) - (Fmi * cph + Fmr * sph)) + cd * Zf;
            Fpr = nFpr; Fpi = nFpi; Fmr = nFmr; Fmi = nFmi; Zf = nZf;
            // EPG shift (lane +/-1; s==0 / s==20 zero-fill masks group edges)
            const float sFpr = __shfl_up(Fpr, 1);
            const float sFpi = __shfl_up(Fpi, 1);
            const float sZf  = __shfl_up(Zf, 1);
            const float sZb  = __shfl_up(Zb, 1);
            const float sFmr = __shfl_down(Fmr, 1);
            const float sFmi = __shfl_down(Fmi, 1);
            const bool s0 = (s == 0), sE = (s == NSTATES - 1);
            Fpr = s0 ? 0.f : sFpr;
            Fpi = s0 ? 0.f : sFpi;
            Zf  = s0 ? 0.f : sZf;
            Zb  = s0 ? 0.f : sZb;
            Fmr = sE ? 0.f : sFmr;
            Fmi = sE ? 0.f : sFmi;
        };

        auto stage_chunk = [&](int c) {   // compute+stage pulses of chunk c
            #pragma unroll
            for (int cp = 0; cp < CHUNK; ++cp) {
                step(fa_arr[c * CHUNK + cp], ph_arr[c * CHUNK + cp]);
                if (valid) {
                    float* dst = &lds[c & 1][cp][lb * RECF + s * 10];
                    ((float2*)dst)[0] = make_float2(Fpr, Fpi);
                    ((float2*)dst)[1] = make_float2(Fmr, Fmi);
                    dst[4] = Zf;
                    dst[9] = Zb;
                }
            }
        };

        stage_chunk(0);                               // prologue
        asm volatile("s_waitcnt lgkmcnt(0)" ::: "memory");
        __builtin_amdgcn_s_barrier();                 // buf0 ready

        for (int c = 0; c < NCHUNK; ++c) {
            if (c + 1 < NCHUNK)
                stage_chunk(c + 1);                   // fills buf[(c+1)&1]
            asm volatile("s_waitcnt lgkmcnt(0)" ::: "memory");
            __builtin_amdgcn_s_barrier();             // chunk c fully written
            // Reuse safety: writers finished READING buf[c&1] before this
            // barrier; compute touches buf[c&1] again only in window c+1.
        }
    } else {
        // ---------------- writer role ----------------
        const int wtid = tid - 256;                   // 0..255

        asm volatile("s_waitcnt lgkmcnt(0)" ::: "memory");
        __builtin_amdgcn_s_barrier();                 // wait buf0 ready

        for (int c = 0; c < NCHUNK; ++c) {
            const float* Lb = (const float*)lds[c & 1];
            #pragma unroll
            for (int cp = 0; cp < CHUNK; ++cp) {
                const v4f* Ls = (const v4f*)(Lb + cp * PFLOATS);
                v4f* og = outb4 + (size_t)(c * CHUNK + cp) * pstride4;
                const int i0 = wtid, i1 = wtid + 256, i2 = wtid + 512;
                v4f t0, t1, t2;
                t0 = Ls[i0];                          // i0 < 256 <= n4 always
                const bool v1 = (i1 < n4), v2 = (i2 < n4);
                if (v1) t1 = Ls[i1];
                if (v2) t2 = Ls[i2];
                og[i0] = t0;                          // back-to-back dwordx4
                if (v1) og[i1] = t1;
                if (v2) og[i2] = t2;
            }
            asm volatile("s_waitcnt lgkmcnt(0)" ::: "memory");  // ds_reads done
            __builtin_amdgcn_s_barrier();             // release buf to compute
            // No vmcnt drain: stores keep floating across chunks.
        }
    }
}

extern "C" void kernel_launch(void* const* d_in, const int* in_sizes, int n_in,
                              void* d_out, int out_size, void* d_ws, size_t ws_size,
                              hipStream_t stream) {
    const float* fa  = (const float*)d_in[0];
    const float* ph  = (const float*)d_in[1];
    const float* T1f = (const float*)d_in[2];
    const float* T2f = (const float*)d_in[3];
    const float* T1b = (const float*)d_in[4];
    const float* T2b = (const float*)d_in[5];
    const float* kf  = (const float*)d_in[6];
    const float* kb  = (const float*)d_in[7];
    const float* B0  = (const float*)d_in[8];
    const float* B1  = (const float*)d_in[9];
    const float* wf  = (const float*)d_in[10];
    const float* wb  = (const float*)d_in[11];
    const int*   TR  = (const int*)d_in[12];
    float* out = (float*)d_out;

    const int blocks = (BATCH + BPB - 1) / BPB;   // 683
    epg_mt_kernel<<<blocks, 512, 0, stream>>>(fa, ph, T1f, T2f, T1b, T2b,
                                              kf, kb, B0, B1, wf, wb, TR, out);
}